// Round 4
// baseline (809.532 us; speedup 1.0000x reference)
//
#include <hip/hip_runtime.h>

#define T_ 32
#define B_ 32
#define S_ 64
#define C_ 1024
#define H_ 1024
#define NWG 256

typedef __attribute__((ext_vector_type(8))) short bf16x8;
typedef __attribute__((ext_vector_type(4))) float f32x4;

// d_out layout (float offsets): outputs[32*32*1024], h[32*1024], c[32*1024], attn[32*32*64]
#define OUT_H   1048576
#define OUT_CC  1081344
#define OUT_AT  1114112

__device__ __forceinline__ ushort f2b(float f) {
  unsigned u = __float_as_uint(f);
  unsigned r = (u + 0x7FFFu + ((u >> 16) & 1u)) >> 16;
  return (ushort)r;
}
__device__ __forceinline__ float b2f(ushort h) {
  return __uint_as_float(((unsigned)h) << 16);
}

// ---------------- convert f32 -> bf16 (8 elems/thread) ----------------
__global__ __launch_bounds__(256) void k_cvt(const float* __restrict__ src, ushort* __restrict__ dst) {
  size_t i = ((size_t)blockIdx.x * 256 + threadIdx.x) * 8;
  float4 v0 = *reinterpret_cast<const float4*>(src + i);
  float4 v1 = *reinterpret_cast<const float4*>(src + i + 4);
  uint4 o;
  o.x = (unsigned)f2b(v0.x) | ((unsigned)f2b(v0.y) << 16);
  o.y = (unsigned)f2b(v0.z) | ((unsigned)f2b(v0.w) << 16);
  o.z = (unsigned)f2b(v1.x) | ((unsigned)f2b(v1.y) << 16);
  o.w = (unsigned)f2b(v1.z) | ((unsigned)f2b(v1.w) << 16);
  *reinterpret_cast<uint4*>(dst + i) = o;
}

// ---------------- prep: v = W2@W1_x, bias, zero h0, zero barrier ----------------
__global__ __launch_bounds__(256) void k_prep(const float* __restrict__ W1, const float* __restrict__ W2,
                                              const float* __restrict__ bih, const float* __restrict__ bhh,
                                              float* __restrict__ v, float* __restrict__ bias,
                                              ushort* __restrict__ h0, unsigned* __restrict__ bar) {
  int blk = blockIdx.x, tid = threadIdx.x;
  if (blk < 4) {
    int c = blk * 256 + tid;
    float acc = 0.f;
#pragma unroll 8
    for (int a = 0; a < 128; ++a) acc += W1[a * 2048 + 1024 + c] * W2[a];
    v[c] = acc;
  } else if (blk < 20) {
    int j = (blk - 4) * 256 + tid;
    bias[j] = bih[j] + bhh[j];
  } else if (blk < 24) {
    unsigned* hz = reinterpret_cast<unsigned*>(h0);
    int base = (blk - 20) * 4096;
    for (int i = 0; i < 16; ++i) hz[base + i * 256 + tid] = 0u;
  } else {
    if (tid < 64) bar[tid] = 0u;
  }
}

// ---------------- attention (time-invariant) ----------------
__global__ __launch_bounds__(256) void k_attn(const float* __restrict__ ctx, const float* __restrict__ v,
                                              float* __restrict__ attn, float* __restrict__ wgt) {
  int b = blockIdx.x, tid = threadIdx.x;
  int lane = tid & 63, w = tid >> 6;
  __shared__ float v_s[1024];
  __shared__ float sc_s[64];
  __shared__ float att_s[64];
  for (int i = 0; i < 4; ++i) v_s[tid + i * 256] = v[tid + i * 256];
  __syncthreads();
  for (int si = 0; si < 16; ++si) {
    int s = w * 16 + si;
    const float* xr = ctx + (size_t)(s * B_ + b) * C_;
    float acc = 0.f;
#pragma unroll
    for (int i = 0; i < 16; ++i) { int c = lane + i * 64; acc += xr[c] * v_s[c]; }
    for (int off = 32; off; off >>= 1) acc += __shfl_down(acc, off);
    if (lane == 0) sc_s[s] = acc;
  }
  __syncthreads();
  if (tid < 64) {
    float val = sc_s[tid];
    float mx = val;
    for (int off = 32; off; off >>= 1) mx = fmaxf(mx, __shfl_xor(mx, off));
    float e = expf(val - mx);
    float sm = e;
    for (int off = 32; off; off >>= 1) sm += __shfl_xor(sm, off);
    float a = e / sm;
    att_s[tid] = a;
    attn[b * 64 + tid] = a;
  }
  __syncthreads();
  const float4* ctx4 = reinterpret_cast<const float4*>(ctx);
  float4 a4 = {0.f, 0.f, 0.f, 0.f};
  for (int s = 0; s < 64; ++s) {
    float a = att_s[s];
    float4 x = ctx4[(size_t)(s * B_ + b) * 256 + tid];
    a4.x += a * x.x; a4.y += a * x.y; a4.z += a * x.z; a4.w += a * x.w;
  }
  reinterpret_cast<float4*>(wgt + b * 1024)[tid] = a4;
}

__global__ __launch_bounds__(256) void k_bcast(const float* __restrict__ wgt, const float* __restrict__ attn,
                                               float* __restrict__ out) {
  int blk = blockIdx.x, tid = threadIdx.x;
  int t = blk >> 5, b = blk & 31;
  const float4* src = reinterpret_cast<const float4*>(wgt + b * 1024);
  float4* dst = reinterpret_cast<float4*>(out + (size_t)(t * B_ + b) * C_);
  dst[tid] = src[tid];
  if (tid < 64) out[OUT_AT + (t * B_ + b) * 64 + tid] = attn[b * 64 + tid];
}

// ---------------- x_proj MFMA: xpT[j][m] = sum_k inp[m][k]*W_ih[j][k] + bias[j] ----------------
__global__ __launch_bounds__(256) void k_xproj(const ushort* __restrict__ inpb, const ushort* __restrict__ Wihb,
                                               const float* __restrict__ bias, ushort* __restrict__ xpT) {
  __shared__ int4 A_s[512];  // fragment-contiguous: [kgrp(4)][row(128)] x 16B
  __shared__ int4 B_s[512];
  int tid = threadIdx.x;
  int m0 = (blockIdx.x >> 5) << 7;
  int j0 = (blockIdx.x & 31) << 7;
  int lane = tid & 63, w = tid >> 6;
  int wm = (w >> 1) * 64, wn = (w & 1) * 64;
  int g = lane >> 4, r = lane & 15;
  f32x4 acc[4][4];
#pragma unroll
  for (int mi = 0; mi < 4; ++mi)
#pragma unroll
    for (int ni = 0; ni < 4; ++ni) acc[mi][ni] = (f32x4)(0.f);

  int f0 = tid, r0s = f0 >> 2, g0s = f0 & 3;
  int f1 = tid + 256, r1s = f1 >> 2, g1s = f1 & 3;
  for (int k0 = 0; k0 < 1024; k0 += 32) {
    __syncthreads();
    A_s[g0s * 128 + r0s] = *reinterpret_cast<const int4*>(inpb + (size_t)(m0 + r0s) * 1024 + k0 + g0s * 8);
    B_s[g0s * 128 + r0s] = *reinterpret_cast<const int4*>(Wihb + (size_t)(j0 + r0s) * 1024 + k0 + g0s * 8);
    A_s[g1s * 128 + r1s] = *reinterpret_cast<const int4*>(inpb + (size_t)(m0 + r1s) * 1024 + k0 + g1s * 8);
    B_s[g1s * 128 + r1s] = *reinterpret_cast<const int4*>(Wihb + (size_t)(j0 + r1s) * 1024 + k0 + g1s * 8);
    __syncthreads();
    bf16x8 af[4], bf_[4];
#pragma unroll
    for (int mi = 0; mi < 4; ++mi) af[mi] = *reinterpret_cast<const bf16x8*>(&A_s[g * 128 + wm + mi * 16 + r]);
#pragma unroll
    for (int ni = 0; ni < 4; ++ni) bf_[ni] = *reinterpret_cast<const bf16x8*>(&B_s[g * 128 + wn + ni * 16 + r]);
#pragma unroll
    for (int mi = 0; mi < 4; ++mi)
#pragma unroll
      for (int ni = 0; ni < 4; ++ni)
        acc[mi][ni] = __builtin_amdgcn_mfma_f32_16x16x32_bf16(af[mi], bf_[ni], acc[mi][ni], 0, 0, 0);
  }
  int q = lane >> 4;
#pragma unroll
  for (int ni = 0; ni < 4; ++ni) {
    int j = j0 + wn + ni * 16 + r;
    float bj = bias[j];
#pragma unroll
    for (int mi = 0; mi < 4; ++mi) {
      int mb = m0 + wm + mi * 16 + q * 4;
      uint2 pk;
      pk.x = (unsigned)f2b(acc[mi][ni][0] + bj) | ((unsigned)f2b(acc[mi][ni][1] + bj) << 16);
      pk.y = (unsigned)f2b(acc[mi][ni][2] + bj) | ((unsigned)f2b(acc[mi][ni][3] + bj) << 16);
      *reinterpret_cast<uint2*>(xpT + (size_t)j * 1024 + mb) = pk;
    }
  }
}

// ---------------- persistent recurrence: all 32 LSTM steps, one dispatch ----------------
// 256 WGs x 256 threads. WG owns hidx [4*wg, 4*wg+4) x all 4 gates (16 gate rows).
// Wave w holds W_hh fragments for K-slice [256w, 256w+256) in registers.
__global__ __launch_bounds__(256) void k_rec(const ushort* __restrict__ Whhb, const ushort* __restrict__ xpT,
                                             ushort* __restrict__ h0, ushort* __restrict__ h1,
                                             float* __restrict__ out, unsigned* __restrict__ bar) {
  int tid = threadIdx.x, lane = tid & 63, w = tid >> 6;
  int wg = blockIdx.x;
  int hidx0 = wg * 4;
  int g = lane >> 4, r = lane & 15;
  int kbase = w * 256;
  // A row r -> gate = r>>2, hi = r&3
  int j = (r >> 2) * 1024 + hidx0 + (r & 3);
  bf16x8 a[8];
  {
    const ushort* ap = Whhb + (size_t)j * 1024 + kbase + g * 8;
#pragma unroll
    for (int kk = 0; kk < 8; ++kk) a[kk] = *reinterpret_cast<const bf16x8*>(ap + kk * 32);
  }
  __shared__ float red[4][16][32];
  float c_reg = 0.f;
  int eb = tid & 31, ehi = tid >> 5;  // epilogue cell (tid<128)

  for (int t = 0; t < T_; ++t) {
    const ushort* hin = (t & 1) ? h1 : h0;
    ushort* hout = (t & 1) ? h0 : h1;
    const ushort* bp0 = hin + (size_t)r * 1024 + kbase + g * 8;
    const ushort* bp1 = bp0 + 16 * 1024;
    f32x4 acc0 = (f32x4)(0.f), acc1 = (f32x4)(0.f);
#pragma unroll
    for (int kk = 0; kk < 8; ++kk) {
      bf16x8 b0 = *reinterpret_cast<const bf16x8*>(bp0 + kk * 32);
      bf16x8 b1 = *reinterpret_cast<const bf16x8*>(bp1 + kk * 32);
      acc0 = __builtin_amdgcn_mfma_f32_16x16x32_bf16(a[kk], b0, acc0, 0, 0, 0);
      acc1 = __builtin_amdgcn_mfma_f32_16x16x32_bf16(a[kk], b1, acc1, 0, 0, 0);
    }
#pragma unroll
    for (int e = 0; e < 4; ++e) {
      red[w][g * 4 + e][r] = acc0[e];
      red[w][g * 4 + e][r + 16] = acc1[e];
    }
    __syncthreads();
    if (tid < 128) {
      int hidx = hidx0 + ehi;
      int m = t * 32 + eb;
      float ig = red[0][0 + ehi][eb]  + red[1][0 + ehi][eb]  + red[2][0 + ehi][eb]  + red[3][0 + ehi][eb]
               + b2f(xpT[(size_t)(hidx) * 1024 + m]);
      float fg = red[0][4 + ehi][eb]  + red[1][4 + ehi][eb]  + red[2][4 + ehi][eb]  + red[3][4 + ehi][eb]
               + b2f(xpT[(size_t)(1024 + hidx) * 1024 + m]);
      float gg = red[0][8 + ehi][eb]  + red[1][8 + ehi][eb]  + red[2][8 + ehi][eb]  + red[3][8 + ehi][eb]
               + b2f(xpT[(size_t)(2048 + hidx) * 1024 + m]);
      float og = red[0][12 + ehi][eb] + red[1][12 + ehi][eb] + red[2][12 + ehi][eb] + red[3][12 + ehi][eb]
               + b2f(xpT[(size_t)(3072 + hidx) * 1024 + m]);
      float si = 1.f / (1.f + __expf(-ig));
      float sf = 1.f / (1.f + __expf(-fg));
      float so = 1.f / (1.f + __expf(-og));
      float c_new = sf * c_reg + si * tanhf(gg);
      float h_new = so * tanhf(c_new);
      c_reg = c_new;
      hout[eb * 1024 + hidx] = f2b(h_new);
      if (t == T_ - 1) {
        out[OUT_H + eb * 1024 + hidx] = h_new;
        out[OUT_CC + eb * 1024 + hidx] = c_new;
      }
    }
    // grid barrier (fresh counter per step; skip after last step)
    if (t != T_ - 1) {
      __syncthreads();
      if (tid == 0) {
        __threadfence();
        atomicAdd(&bar[t], 1u);
        while (atomicAdd(&bar[t], 0u) < (unsigned)NWG) { __builtin_amdgcn_s_sleep(2); }
        __threadfence();
      }
      __syncthreads();
    }
  }
}

extern "C" void kernel_launch(void* const* d_in, const int* in_sizes, int n_in,
                              void* d_out, int out_size, void* d_ws, size_t ws_size,
                              hipStream_t stream) {
  const float* inp = (const float*)d_in[0];
  const float* ctx = (const float*)d_in[1];
  const float* Wih = (const float*)d_in[2];
  const float* Whh = (const float*)d_in[3];
  const float* bih = (const float*)d_in[4];
  const float* bhh = (const float*)d_in[5];
  const float* W1  = (const float*)d_in[6];
  const float* W2  = (const float*)d_in[8];
  float* out = (float*)d_out;
  char* wsb = (char*)d_ws;

  float* v    = (float*)(wsb + 0);          // 4 KB
  float* bias = (float*)(wsb + 4096);       // 16 KB
  float* attn = (float*)(wsb + 20480);      // 8 KB
  float* wgt  = (float*)(wsb + 28672);      // 128 KB
  ushort* h0   = (ushort*)(wsb + 163840);   // 64 KB
  ushort* h1   = (ushort*)(wsb + 229376);   // 64 KB
  ushort* inpb = (ushort*)(wsb + 294912);   // 2 MB
  ushort* Wihb = (ushort*)(wsb + 2392064);  // 8 MB
  ushort* Whhb = (ushort*)(wsb + 10780672); // 8 MB
  ushort* xpT  = (ushort*)(wsb + 19169280); // 8 MB
  unsigned* bar = (unsigned*)(wsb + 27557888); // 256 B

  hipLaunchKernelGGL(k_prep, dim3(25), dim3(256), 0, stream, W1, W2, bih, bhh, v, bias, h0, bar);
  hipLaunchKernelGGL(k_cvt, dim3(512), dim3(256), 0, stream, inp, inpb);
  hipLaunchKernelGGL(k_cvt, dim3(2048), dim3(256), 0, stream, Wih, Wihb);
  hipLaunchKernelGGL(k_cvt, dim3(2048), dim3(256), 0, stream, Whh, Whhb);
  hipLaunchKernelGGL(k_attn, dim3(32), dim3(256), 0, stream, ctx, v, attn, wgt);
  hipLaunchKernelGGL(k_bcast, dim3(1024), dim3(256), 0, stream, wgt, attn, out);
  hipLaunchKernelGGL(k_xproj, dim3(256), dim3(256), 0, stream, inpb, Wihb, bias, xpT);

  const ushort* Whhb_c = Whhb;
  const ushort* xpT_c = xpT;
  void* kargs[6];
  kargs[0] = (void*)&Whhb_c;
  kargs[1] = (void*)&xpT_c;
  kargs[2] = (void*)&h0;
  kargs[3] = (void*)&h1;
  kargs[4] = (void*)&out;
  kargs[5] = (void*)&bar;
  hipLaunchCooperativeKernel((const void*)k_rec, dim3(NWG), dim3(256), kargs, 0, stream);
}

// Round 5
// 534.561 us; speedup vs baseline: 1.5144x; 1.5144x over previous
//
#include <hip/hip_runtime.h>

#define T_ 32
#define B_ 32
#define S_ 64
#define C_ 1024
#define H_ 1024
#define NWG 64

typedef __attribute__((ext_vector_type(8))) short bf16x8;
typedef __attribute__((ext_vector_type(4))) float f32x4;

// d_out layout (float offsets): outputs[32*32*1024], h[32*1024], c[32*1024], attn[32*32*64]
#define OUT_H   1048576
#define OUT_CC  1081344
#define OUT_AT  1114112

__device__ __forceinline__ ushort f2b(float f) {
  unsigned u = __float_as_uint(f);
  unsigned r = (u + 0x7FFFu + ((u >> 16) & 1u)) >> 16;
  return (ushort)r;
}
__device__ __forceinline__ float b2f(ushort h) {
  return __uint_as_float(((unsigned)h) << 16);
}

// ---------------- convert f32 -> bf16 (8 elems/thread) ----------------
__global__ __launch_bounds__(256) void k_cvt(const float* __restrict__ src, ushort* __restrict__ dst) {
  size_t i = ((size_t)blockIdx.x * 256 + threadIdx.x) * 8;
  float4 v0 = *reinterpret_cast<const float4*>(src + i);
  float4 v1 = *reinterpret_cast<const float4*>(src + i + 4);
  uint4 o;
  o.x = (unsigned)f2b(v0.x) | ((unsigned)f2b(v0.y) << 16);
  o.y = (unsigned)f2b(v0.z) | ((unsigned)f2b(v0.w) << 16);
  o.z = (unsigned)f2b(v1.x) | ((unsigned)f2b(v1.y) << 16);
  o.w = (unsigned)f2b(v1.z) | ((unsigned)f2b(v1.w) << 16);
  *reinterpret_cast<uint4*>(dst + i) = o;
}

// ---------------- prep: v = W2@W1_x, bias, zero h0, zero barrier ----------------
__global__ __launch_bounds__(256) void k_prep(const float* __restrict__ W1, const float* __restrict__ W2,
                                              const float* __restrict__ bih, const float* __restrict__ bhh,
                                              float* __restrict__ v, float* __restrict__ bias,
                                              ushort* __restrict__ h0, unsigned* __restrict__ bar) {
  int blk = blockIdx.x, tid = threadIdx.x;
  if (blk < 4) {
    int c = blk * 256 + tid;
    float acc = 0.f;
#pragma unroll 8
    for (int a = 0; a < 128; ++a) acc += W1[a * 2048 + 1024 + c] * W2[a];
    v[c] = acc;
  } else if (blk < 20) {
    int j = (blk - 4) * 256 + tid;
    bias[j] = bih[j] + bhh[j];
  } else if (blk < 24) {
    unsigned* hz = reinterpret_cast<unsigned*>(h0);
    int base = (blk - 20) * 4096;
    for (int i = 0; i < 16; ++i) hz[base + i * 256 + tid] = 0u;
  } else {
    bar[tid] = 0u;
  }
}

// ---------------- attention (time-invariant) ----------------
__global__ __launch_bounds__(256) void k_attn(const float* __restrict__ ctx, const float* __restrict__ v,
                                              float* __restrict__ attn, float* __restrict__ wgt) {
  int b = blockIdx.x, tid = threadIdx.x;
  int lane = tid & 63, w = tid >> 6;
  __shared__ float v_s[1024];
  __shared__ float sc_s[64];
  __shared__ float att_s[64];
  for (int i = 0; i < 4; ++i) v_s[tid + i * 256] = v[tid + i * 256];
  __syncthreads();
  for (int si = 0; si < 16; ++si) {
    int s = w * 16 + si;
    const float* xr = ctx + (size_t)(s * B_ + b) * C_;
    float acc = 0.f;
#pragma unroll
    for (int i = 0; i < 16; ++i) { int c = lane + i * 64; acc += xr[c] * v_s[c]; }
    for (int off = 32; off; off >>= 1) acc += __shfl_down(acc, off);
    if (lane == 0) sc_s[s] = acc;
  }
  __syncthreads();
  if (tid < 64) {
    float val = sc_s[tid];
    float mx = val;
    for (int off = 32; off; off >>= 1) mx = fmaxf(mx, __shfl_xor(mx, off));
    float e = expf(val - mx);
    float sm = e;
    for (int off = 32; off; off >>= 1) sm += __shfl_xor(sm, off);
    float a = e / sm;
    att_s[tid] = a;
    attn[b * 64 + tid] = a;
  }
  __syncthreads();
  const float4* ctx4 = reinterpret_cast<const float4*>(ctx);
  float4 a4 = {0.f, 0.f, 0.f, 0.f};
  for (int s = 0; s < 64; ++s) {
    float a = att_s[s];
    float4 x = ctx4[(size_t)(s * B_ + b) * 256 + tid];
    a4.x += a * x.x; a4.y += a * x.y; a4.z += a * x.z; a4.w += a * x.w;
  }
  reinterpret_cast<float4*>(wgt + b * 1024)[tid] = a4;
}

__global__ __launch_bounds__(256) void k_bcast(const float* __restrict__ wgt, const float* __restrict__ attn,
                                               float* __restrict__ out) {
  int blk = blockIdx.x, tid = threadIdx.x;
  int t = blk >> 5, b = blk & 31;
  const float4* src = reinterpret_cast<const float4*>(wgt + b * 1024);
  float4* dst = reinterpret_cast<float4*>(out + (size_t)(t * B_ + b) * C_);
  dst[tid] = src[tid];
  if (tid < 64) out[OUT_AT + (t * B_ + b) * 64 + tid] = attn[b * 64 + tid];
}

// ---------------- x_proj MFMA: xpT[j][m] = sum_k inp[m][k]*W_ih[j][k] + bias[j] ----------------
__global__ __launch_bounds__(256) void k_xproj(const ushort* __restrict__ inpb, const ushort* __restrict__ Wihb,
                                               const float* __restrict__ bias, ushort* __restrict__ xpT) {
  __shared__ int4 A_s[512];  // fragment-contiguous: [kgrp(4)][row(128)] x 16B
  __shared__ int4 B_s[512];
  int tid = threadIdx.x;
  int m0 = (blockIdx.x >> 5) << 7;
  int j0 = (blockIdx.x & 31) << 7;
  int lane = tid & 63, w = tid >> 6;
  int wm = (w >> 1) * 64, wn = (w & 1) * 64;
  int g = lane >> 4, r = lane & 15;
  f32x4 acc[4][4];
#pragma unroll
  for (int mi = 0; mi < 4; ++mi)
#pragma unroll
    for (int ni = 0; ni < 4; ++ni) acc[mi][ni] = (f32x4)(0.f);

  int f0 = tid, r0s = f0 >> 2, g0s = f0 & 3;
  int f1 = tid + 256, r1s = f1 >> 2, g1s = f1 & 3;
  for (int k0 = 0; k0 < 1024; k0 += 32) {
    __syncthreads();
    A_s[g0s * 128 + r0s] = *reinterpret_cast<const int4*>(inpb + (size_t)(m0 + r0s) * 1024 + k0 + g0s * 8);
    B_s[g0s * 128 + r0s] = *reinterpret_cast<const int4*>(Wihb + (size_t)(j0 + r0s) * 1024 + k0 + g0s * 8);
    A_s[g1s * 128 + r1s] = *reinterpret_cast<const int4*>(inpb + (size_t)(m0 + r1s) * 1024 + k0 + g1s * 8);
    B_s[g1s * 128 + r1s] = *reinterpret_cast<const int4*>(Wihb + (size_t)(j0 + r1s) * 1024 + k0 + g1s * 8);
    __syncthreads();
    bf16x8 af[4], bf_[4];
#pragma unroll
    for (int mi = 0; mi < 4; ++mi) af[mi] = *reinterpret_cast<const bf16x8*>(&A_s[g * 128 + wm + mi * 16 + r]);
#pragma unroll
    for (int ni = 0; ni < 4; ++ni) bf_[ni] = *reinterpret_cast<const bf16x8*>(&B_s[g * 128 + wn + ni * 16 + r]);
#pragma unroll
    for (int mi = 0; mi < 4; ++mi)
#pragma unroll
      for (int ni = 0; ni < 4; ++ni)
        acc[mi][ni] = __builtin_amdgcn_mfma_f32_16x16x32_bf16(af[mi], bf_[ni], acc[mi][ni], 0, 0, 0);
  }
  int q = lane >> 4;
#pragma unroll
  for (int ni = 0; ni < 4; ++ni) {
    int j = j0 + wn + ni * 16 + r;
    float bj = bias[j];
#pragma unroll
    for (int mi = 0; mi < 4; ++mi) {
      int mb = m0 + wm + mi * 16 + q * 4;
      uint2 pk;
      pk.x = (unsigned)f2b(acc[mi][ni][0] + bj) | ((unsigned)f2b(acc[mi][ni][1] + bj) << 16);
      pk.y = (unsigned)f2b(acc[mi][ni][2] + bj) | ((unsigned)f2b(acc[mi][ni][3] + bj) << 16);
      *reinterpret_cast<uint2*>(xpT + (size_t)j * 1024 + mb) = pk;
    }
  }
}

// ---------------- persistent recurrence: all 32 LSTM steps, one dispatch ----------------
// 64 WGs x 1024 threads (16 waves). WG owns hidx [16*wg, 16*wg+16) x all 4 gates.
// Wave w: hidx-quad q=w&3, K-slice ks=w>>2 (256 wide). W_hh fragments in registers.
__global__ __launch_bounds__(1024, 4) void k_rec(const ushort* __restrict__ Whhb, const ushort* __restrict__ xpT,
                                                 ushort* __restrict__ h0, ushort* __restrict__ h1,
                                                 float* __restrict__ out, unsigned* __restrict__ bar) {
  int tid = threadIdx.x, lane = tid & 63, w = tid >> 6;
  int wg = blockIdx.x;
  int q = w & 3, ks = w >> 2;
  int g = lane >> 4, r = lane & 15;
  int hidx0 = wg * 16 + q * 4;
  int kbase = ks * 256;
  int j = (r >> 2) * 1024 + hidx0 + (r & 3);
  bf16x8 a[8];
  {
    const ushort* ap = Whhb + (size_t)j * 1024 + kbase + g * 8;
#pragma unroll
    for (int kk = 0; kk < 8; ++kk) a[kk] = *reinterpret_cast<const bf16x8*>(ap + kk * 32);
  }
  __shared__ float red[4][4][16][32];
  __shared__ __align__(16) ushort hs[32][24];
  float c_reg = 0.f;
  int eb = tid & 31, hl = (tid >> 5) & 3, qq = tid >> 7;  // epilogue cell (tid<512)

  for (int t = 0; t < T_; ++t) {
    const ushort* hin = (t & 1) ? h1 : h0;
    ushort* hout = (t & 1) ? h0 : h1;
    const ushort* bp0 = hin + (size_t)r * 1024 + kbase + g * 8;
    const ushort* bp1 = bp0 + 16 * 1024;
    f32x4 acc0 = (f32x4)(0.f), acc1 = (f32x4)(0.f);
#pragma unroll
    for (int kk = 0; kk < 8; ++kk) {
      bf16x8 b0 = *reinterpret_cast<const bf16x8*>(bp0 + kk * 32);
      bf16x8 b1 = *reinterpret_cast<const bf16x8*>(bp1 + kk * 32);
      acc0 = __builtin_amdgcn_mfma_f32_16x16x32_bf16(a[kk], b0, acc0, 0, 0, 0);
      acc1 = __builtin_amdgcn_mfma_f32_16x16x32_bf16(a[kk], b1, acc1, 0, 0, 0);
    }
#pragma unroll
    for (int e = 0; e < 4; ++e) {
      red[q][ks][g * 4 + e][r] = acc0[e];
      red[q][ks][g * 4 + e][r + 16] = acc1[e];
    }
    __syncthreads();
    if (tid < 512) {
      int hidx = wg * 16 + qq * 4 + hl;
      int m = t * 32 + eb;
      float ig = red[qq][0][0 + hl][eb]  + red[qq][1][0 + hl][eb]  + red[qq][2][0 + hl][eb]  + red[qq][3][0 + hl][eb]
               + b2f(xpT[(size_t)(hidx) * 1024 + m]);
      float fg = red[qq][0][4 + hl][eb]  + red[qq][1][4 + hl][eb]  + red[qq][2][4 + hl][eb]  + red[qq][3][4 + hl][eb]
               + b2f(xpT[(size_t)(1024 + hidx) * 1024 + m]);
      float gg = red[qq][0][8 + hl][eb]  + red[qq][1][8 + hl][eb]  + red[qq][2][8 + hl][eb]  + red[qq][3][8 + hl][eb]
               + b2f(xpT[(size_t)(2048 + hidx) * 1024 + m]);
      float og = red[qq][0][12 + hl][eb] + red[qq][1][12 + hl][eb] + red[qq][2][12 + hl][eb] + red[qq][3][12 + hl][eb]
               + b2f(xpT[(size_t)(3072 + hidx) * 1024 + m]);
      float si = 1.f / (1.f + __expf(-ig));
      float sf = 1.f / (1.f + __expf(-fg));
      float so = 1.f / (1.f + __expf(-og));
      float c_new = sf * c_reg + si * tanhf(gg);
      float h_new = so * tanhf(c_new);
      c_reg = c_new;
      hs[eb][qq * 4 + hl] = f2b(h_new);
      if (t == T_ - 1) {
        out[OUT_H + eb * 1024 + hidx] = h_new;
        out[OUT_CC + eb * 1024 + hidx] = c_new;
      }
    }
    if (t != T_ - 1) {
      __syncthreads();
      if (tid < 64) {
        int b = tid >> 1, half = tid & 1;
        uint4 vv = *reinterpret_cast<const uint4*>(&hs[b][half * 8]);
        *reinterpret_cast<uint4*>(hout + (size_t)b * 1024 + wg * 16 + half * 8) = vv;
      }
      // grid barrier: spread arrivals over 8 counters, poll with atomic LOADS (no RMW spin)
      __syncthreads();
      if (tid == 0) {
        __threadfence();
        __hip_atomic_fetch_add(&bar[t * 8 + (wg & 7)], 1u, __ATOMIC_RELAXED, __HIP_MEMORY_SCOPE_AGENT);
        unsigned sum;
        do {
          sum = 0;
#pragma unroll
          for (int i = 0; i < 8; ++i)
            sum += __hip_atomic_load(&bar[t * 8 + i], __ATOMIC_RELAXED, __HIP_MEMORY_SCOPE_AGENT);
          if (sum < (unsigned)NWG) __builtin_amdgcn_s_sleep(4);
        } while (sum < (unsigned)NWG);
        __threadfence();
      }
      __syncthreads();
    }
  }
}

extern "C" void kernel_launch(void* const* d_in, const int* in_sizes, int n_in,
                              void* d_out, int out_size, void* d_ws, size_t ws_size,
                              hipStream_t stream) {
  const float* inp = (const float*)d_in[0];
  const float* ctx = (const float*)d_in[1];
  const float* Wih = (const float*)d_in[2];
  const float* Whh = (const float*)d_in[3];
  const float* bih = (const float*)d_in[4];
  const float* bhh = (const float*)d_in[5];
  const float* W1  = (const float*)d_in[6];
  const float* W2  = (const float*)d_in[8];
  float* out = (float*)d_out;
  char* wsb = (char*)d_ws;

  float* v    = (float*)(wsb + 0);          // 4 KB
  float* bias = (float*)(wsb + 4096);       // 16 KB
  float* attn = (float*)(wsb + 20480);      // 8 KB
  float* wgt  = (float*)(wsb + 28672);      // 128 KB
  ushort* h0   = (ushort*)(wsb + 163840);   // 64 KB
  ushort* h1   = (ushort*)(wsb + 229376);   // 64 KB
  ushort* inpb = (ushort*)(wsb + 294912);   // 2 MB
  ushort* Wihb = (ushort*)(wsb + 2392064);  // 8 MB
  ushort* Whhb = (ushort*)(wsb + 10780672); // 8 MB
  ushort* xpT  = (ushort*)(wsb + 19169280); // 8 MB
  unsigned* bar = (unsigned*)(wsb + 27557888); // 1 KB (256 counters)

  hipLaunchKernelGGL(k_prep, dim3(25), dim3(256), 0, stream, W1, W2, bih, bhh, v, bias, h0, bar);
  hipLaunchKernelGGL(k_cvt, dim3(512), dim3(256), 0, stream, inp, inpb);
  hipLaunchKernelGGL(k_cvt, dim3(2048), dim3(256), 0, stream, Wih, Wihb);
  hipLaunchKernelGGL(k_cvt, dim3(2048), dim3(256), 0, stream, Whh, Whhb);
  hipLaunchKernelGGL(k_attn, dim3(32), dim3(256), 0, stream, ctx, v, attn, wgt);
  hipLaunchKernelGGL(k_bcast, dim3(1024), dim3(256), 0, stream, wgt, attn, out);
  hipLaunchKernelGGL(k_xproj, dim3(256), dim3(256), 0, stream, inpb, Wihb, bias, xpT);

  const ushort* Whhb_c = Whhb;
  const ushort* xpT_c = xpT;
  void* kargs[6];
  kargs[0] = (void*)&Whhb_c;
  kargs[1] = (void*)&xpT_c;
  kargs[2] = (void*)&h0;
  kargs[3] = (void*)&h1;
  kargs[4] = (void*)&out;
  kargs[5] = (void*)&bar;
  hipLaunchCooperativeKernel((const void*)k_rec, dim3(NWG), dim3(1024), kargs, 0, stream);
}

// Round 6
// 402.586 us; speedup vs baseline: 2.0108x; 1.3278x over previous
//
#include <hip/hip_runtime.h>

#define T_ 32
#define B_ 32
#define S_ 64
#define C_ 1024
#define H_ 1024
#define NWG 64

typedef __attribute__((ext_vector_type(8))) short bf16x8;
typedef __attribute__((ext_vector_type(4))) float f32x4;

// d_out layout (float offsets): outputs[32*32*1024], h[32*1024], c[32*1024], attn[32*32*64]
#define OUT_H   1048576
#define OUT_CC  1081344
#define OUT_AT  1114112

__device__ __forceinline__ ushort f2b(float f) {
  unsigned u = __float_as_uint(f);
  unsigned r = (u + 0x7FFFu + ((u >> 16) & 1u)) >> 16;
  return (ushort)r;
}
__device__ __forceinline__ float b2f(ushort h) {
  return __uint_as_float(((unsigned)h) << 16);
}

// ---------------- convert f32 -> bf16, 3 arrays in one launch ----------------
// blocks [0,512): inp (1M elems); [512,2560): Wih (4M); [2560,4608): Whh (4M)
__global__ __launch_bounds__(256) void k_cvt3(const float* __restrict__ s0, ushort* __restrict__ d0,
                                              const float* __restrict__ s1, ushort* __restrict__ d1,
                                              const float* __restrict__ s2, ushort* __restrict__ d2) {
  int blk = blockIdx.x;
  const float* src;
  ushort* dst;
  int base;
  if (blk < 512) { src = s0; dst = d0; base = blk; }
  else if (blk < 2560) { src = s1; dst = d1; base = blk - 512; }
  else { src = s2; dst = d2; base = blk - 2560; }
  size_t i = ((size_t)base * 256 + threadIdx.x) * 8;
  float4 v0 = *reinterpret_cast<const float4*>(src + i);
  float4 v1 = *reinterpret_cast<const float4*>(src + i + 4);
  uint4 o;
  o.x = (unsigned)f2b(v0.x) | ((unsigned)f2b(v0.y) << 16);
  o.y = (unsigned)f2b(v0.z) | ((unsigned)f2b(v0.w) << 16);
  o.z = (unsigned)f2b(v1.x) | ((unsigned)f2b(v1.y) << 16);
  o.w = (unsigned)f2b(v1.z) | ((unsigned)f2b(v1.w) << 16);
  *reinterpret_cast<uint4*>(dst + i) = o;
}

// ---------------- prep: v = W2@W1_x, bias, zero h0, zero flags ----------------
__global__ __launch_bounds__(256) void k_prep(const float* __restrict__ W1, const float* __restrict__ W2,
                                              const float* __restrict__ bih, const float* __restrict__ bhh,
                                              float* __restrict__ v, float* __restrict__ bias,
                                              ushort* __restrict__ h0, unsigned* __restrict__ flags) {
  int blk = blockIdx.x, tid = threadIdx.x;
  if (blk < 4) {
    int c = blk * 256 + tid;
    float acc = 0.f;
#pragma unroll 8
    for (int a = 0; a < 128; ++a) acc += W1[a * 2048 + 1024 + c] * W2[a];
    v[c] = acc;
  } else if (blk < 20) {
    int j = (blk - 4) * 256 + tid;
    bias[j] = bih[j] + bhh[j];
  } else if (blk < 24) {
    unsigned* hz = reinterpret_cast<unsigned*>(h0);
    int base = (blk - 20) * 4096;
    for (int i = 0; i < 16; ++i) hz[base + i * 256 + tid] = 0u;
  } else {
    for (int i = 0; i < 4; ++i) flags[i * 256 + tid] = 0u;
  }
}

// ---------------- attention (time-invariant) ----------------
__global__ __launch_bounds__(256) void k_attn(const float* __restrict__ ctx, const float* __restrict__ v,
                                              float* __restrict__ attn, float* __restrict__ wgt) {
  int b = blockIdx.x, tid = threadIdx.x;
  int lane = tid & 63, w = tid >> 6;
  __shared__ float v_s[1024];
  __shared__ float sc_s[64];
  __shared__ float att_s[64];
  for (int i = 0; i < 4; ++i) v_s[tid + i * 256] = v[tid + i * 256];
  __syncthreads();
  for (int si = 0; si < 16; ++si) {
    int s = w * 16 + si;
    const float* xr = ctx + (size_t)(s * B_ + b) * C_;
    float acc = 0.f;
#pragma unroll
    for (int i = 0; i < 16; ++i) { int c = lane + i * 64; acc += xr[c] * v_s[c]; }
    for (int off = 32; off; off >>= 1) acc += __shfl_down(acc, off);
    if (lane == 0) sc_s[s] = acc;
  }
  __syncthreads();
  if (tid < 64) {
    float val = sc_s[tid];
    float mx = val;
    for (int off = 32; off; off >>= 1) mx = fmaxf(mx, __shfl_xor(mx, off));
    float e = expf(val - mx);
    float sm = e;
    for (int off = 32; off; off >>= 1) sm += __shfl_xor(sm, off);
    float a = e / sm;
    att_s[tid] = a;
    attn[b * 64 + tid] = a;
  }
  __syncthreads();
  const float4* ctx4 = reinterpret_cast<const float4*>(ctx);
  float4 a4 = {0.f, 0.f, 0.f, 0.f};
  for (int s = 0; s < 64; ++s) {
    float a = att_s[s];
    float4 x = ctx4[(size_t)(s * B_ + b) * 256 + tid];
    a4.x += a * x.x; a4.y += a * x.y; a4.z += a * x.z; a4.w += a * x.w;
  }
  reinterpret_cast<float4*>(wgt + b * 1024)[tid] = a4;
}

__global__ __launch_bounds__(256) void k_bcast(const float* __restrict__ wgt, const float* __restrict__ attn,
                                               float* __restrict__ out) {
  int blk = blockIdx.x, tid = threadIdx.x;
  int t = blk >> 5, b = blk & 31;
  const float4* src = reinterpret_cast<const float4*>(wgt + b * 1024);
  float4* dst = reinterpret_cast<float4*>(out + (size_t)(t * B_ + b) * C_);
  dst[tid] = src[tid];
  if (tid < 64) out[OUT_AT + (t * B_ + b) * 64 + tid] = attn[b * 64 + tid];
}

// ---------------- x_proj MFMA: xpT[j][m] = sum_k inp[m][k]*W_ih[j][k] + bias[j] ----------------
__global__ __launch_bounds__(256) void k_xproj(const ushort* __restrict__ inpb, const ushort* __restrict__ Wihb,
                                               const float* __restrict__ bias, ushort* __restrict__ xpT) {
  __shared__ int4 A_s[512];  // fragment-contiguous: [kgrp(4)][row(128)] x 16B
  __shared__ int4 B_s[512];
  int tid = threadIdx.x;
  int m0 = (blockIdx.x >> 5) << 7;
  int j0 = (blockIdx.x & 31) << 7;
  int lane = tid & 63, w = tid >> 6;
  int wm = (w >> 1) * 64, wn = (w & 1) * 64;
  int g = lane >> 4, r = lane & 15;
  f32x4 acc[4][4];
#pragma unroll
  for (int mi = 0; mi < 4; ++mi)
#pragma unroll
    for (int ni = 0; ni < 4; ++ni) acc[mi][ni] = (f32x4)(0.f);

  int f0 = tid, r0s = f0 >> 2, g0s = f0 & 3;
  int f1 = tid + 256, r1s = f1 >> 2, g1s = f1 & 3;
  for (int k0 = 0; k0 < 1024; k0 += 32) {
    __syncthreads();
    A_s[g0s * 128 + r0s] = *reinterpret_cast<const int4*>(inpb + (size_t)(m0 + r0s) * 1024 + k0 + g0s * 8);
    B_s[g0s * 128 + r0s] = *reinterpret_cast<const int4*>(Wihb + (size_t)(j0 + r0s) * 1024 + k0 + g0s * 8);
    A_s[g1s * 128 + r1s] = *reinterpret_cast<const int4*>(inpb + (size_t)(m0 + r1s) * 1024 + k0 + g1s * 8);
    B_s[g1s * 128 + r1s] = *reinterpret_cast<const int4*>(Wihb + (size_t)(j0 + r1s) * 1024 + k0 + g1s * 8);
    __syncthreads();
    bf16x8 af[4], bf_[4];
#pragma unroll
    for (int mi = 0; mi < 4; ++mi) af[mi] = *reinterpret_cast<const bf16x8*>(&A_s[g * 128 + wm + mi * 16 + r]);
#pragma unroll
    for (int ni = 0; ni < 4; ++ni) bf_[ni] = *reinterpret_cast<const bf16x8*>(&B_s[g * 128 + wn + ni * 16 + r]);
#pragma unroll
    for (int mi = 0; mi < 4; ++mi)
#pragma unroll
      for (int ni = 0; ni < 4; ++ni)
        acc[mi][ni] = __builtin_amdgcn_mfma_f32_16x16x32_bf16(af[mi], bf_[ni], acc[mi][ni], 0, 0, 0);
  }
  int q = lane >> 4;
#pragma unroll
  for (int ni = 0; ni < 4; ++ni) {
    int j = j0 + wn + ni * 16 + r;
    float bj = bias[j];
#pragma unroll
    for (int mi = 0; mi < 4; ++mi) {
      int mb = m0 + wm + mi * 16 + q * 4;
      uint2 pk;
      pk.x = (unsigned)f2b(acc[mi][ni][0] + bj) | ((unsigned)f2b(acc[mi][ni][1] + bj) << 16);
      pk.y = (unsigned)f2b(acc[mi][ni][2] + bj) | ((unsigned)f2b(acc[mi][ni][3] + bj) << 16);
      *reinterpret_cast<uint2*>(xpT + (size_t)j * 1024 + mb) = pk;
    }
  }
}

// ---------------- persistent recurrence: all 32 LSTM steps, one dispatch ----------------
// 64 WGs x 1024 threads (16 waves). WG owns hidx [16*wg, 16*wg+16) x all 4 gates.
// Wave w: hidx-quad q=w&3, K-slice ks=w>>2 (256 wide). W_hh fragments in registers.
// h published via L2-bypass (agent-scope) dword stores + per-WG monotonic flag; readers
// poll 64 flags with one 64-lane load, then one acquire fence (buffer_inv) per step.
__global__ __launch_bounds__(1024, 4) void k_rec(const ushort* __restrict__ Whhb, const ushort* __restrict__ xpT,
                                                 ushort* __restrict__ h0, ushort* __restrict__ h1,
                                                 float* __restrict__ out, unsigned* __restrict__ flags) {
  int tid = threadIdx.x, lane = tid & 63, w = tid >> 6;
  int wg = blockIdx.x;
  int q = w & 3, ks = w >> 2;
  int g = lane >> 4, r = lane & 15;
  int hidx0 = wg * 16 + q * 4;
  int kbase = ks * 256;
  int j = (r >> 2) * 1024 + hidx0 + (r & 3);
  bf16x8 a[8];
  {
    const ushort* ap = Whhb + (size_t)j * 1024 + kbase + g * 8;
#pragma unroll
    for (int kk = 0; kk < 8; ++kk) a[kk] = *reinterpret_cast<const bf16x8*>(ap + kk * 32);
  }
  __shared__ float red[4][4][16][32];
  __shared__ __align__(16) ushort hs[32][16];
  float c_reg = 0.f;
  int eb = tid & 31, hl = (tid >> 5) & 3, qq = tid >> 7;  // epilogue cell (tid<512)
  int ehidx = wg * 16 + qq * 4 + hl;

  // prefetch xpT slice for t=0
  float xf_i = 0.f, xf_f = 0.f, xf_g = 0.f, xf_o = 0.f;
  if (tid < 512) {
    xf_i = b2f(xpT[(size_t)(ehidx) * 1024 + eb]);
    xf_f = b2f(xpT[(size_t)(1024 + ehidx) * 1024 + eb]);
    xf_g = b2f(xpT[(size_t)(2048 + ehidx) * 1024 + eb]);
    xf_o = b2f(xpT[(size_t)(3072 + ehidx) * 1024 + eb]);
  }

#pragma unroll 1
  for (int t = 0; t < T_; ++t) {
    const ushort* hin = (t & 1) ? h1 : h0;
    ushort* hout = (t & 1) ? h0 : h1;
    const ushort* bp0 = hin + (size_t)r * 1024 + kbase + g * 8;
    const ushort* bp1 = bp0 + 16 * 1024;
    f32x4 acc0 = (f32x4)(0.f), acc1 = (f32x4)(0.f);
#pragma unroll
    for (int kk = 0; kk < 8; ++kk) {
      bf16x8 b0 = *reinterpret_cast<const bf16x8*>(bp0 + kk * 32);
      bf16x8 b1 = *reinterpret_cast<const bf16x8*>(bp1 + kk * 32);
      acc0 = __builtin_amdgcn_mfma_f32_16x16x32_bf16(a[kk], b0, acc0, 0, 0, 0);
      acc1 = __builtin_amdgcn_mfma_f32_16x16x32_bf16(a[kk], b1, acc1, 0, 0, 0);
    }
#pragma unroll
    for (int e = 0; e < 4; ++e) {
      red[q][ks][g * 4 + e][r] = acc0[e];
      red[q][ks][g * 4 + e][r + 16] = acc1[e];
    }
    __syncthreads();
    if (tid < 512) {
      float ig = red[qq][0][0 + hl][eb]  + red[qq][1][0 + hl][eb]  + red[qq][2][0 + hl][eb]  + red[qq][3][0 + hl][eb]  + xf_i;
      float fg = red[qq][0][4 + hl][eb]  + red[qq][1][4 + hl][eb]  + red[qq][2][4 + hl][eb]  + red[qq][3][4 + hl][eb]  + xf_f;
      float gg = red[qq][0][8 + hl][eb]  + red[qq][1][8 + hl][eb]  + red[qq][2][8 + hl][eb]  + red[qq][3][8 + hl][eb]  + xf_g;
      float og = red[qq][0][12 + hl][eb] + red[qq][1][12 + hl][eb] + red[qq][2][12 + hl][eb] + red[qq][3][12 + hl][eb] + xf_o;
      float si = 1.f / (1.f + __expf(-ig));
      float sf = 1.f / (1.f + __expf(-fg));
      float so = 1.f / (1.f + __expf(-og));
      float c_new = sf * c_reg + si * tanhf(gg);
      float h_new = so * tanhf(c_new);
      c_reg = c_new;
      hs[eb][qq * 4 + hl] = f2b(h_new);
      if (t == T_ - 1) {
        out[OUT_H + eb * 1024 + ehidx] = h_new;
        out[OUT_CC + eb * 1024 + ehidx] = c_new;
      }
    }
    if (t != T_ - 1) {
      __syncthreads();  // hs ready
      int mnext = (t + 1) * 32 + eb;
      if (w == 0) {
        // publish h slice via L2-bypass dword stores (visible at coherence point, no wbl2)
        int b = lane >> 1, half = lane & 1;
        uint4 vv = *reinterpret_cast<const uint4*>(&hs[b][half * 8]);
        unsigned* hp = reinterpret_cast<unsigned*>(hout) + b * 512 + wg * 8 + half * 4;
        __hip_atomic_store(hp + 0, vv.x, __ATOMIC_RELAXED, __HIP_MEMORY_SCOPE_AGENT);
        __hip_atomic_store(hp + 1, vv.y, __ATOMIC_RELAXED, __HIP_MEMORY_SCOPE_AGENT);
        __hip_atomic_store(hp + 2, vv.z, __ATOMIC_RELAXED, __HIP_MEMORY_SCOPE_AGENT);
        __hip_atomic_store(hp + 3, vv.w, __ATOMIC_RELAXED, __HIP_MEMORY_SCOPE_AGENT);
        asm volatile("s_waitcnt vmcnt(0)" ::: "memory");
        if (lane == 0)
          __hip_atomic_store(&flags[wg * 16], (unsigned)(t + 1), __ATOMIC_RELAXED, __HIP_MEMORY_SCOPE_AGENT);
      }
      // prefetch next xpT slice (overlaps the poll)
      float nx_i = 0.f, nx_f = 0.f, nx_g = 0.f, nx_o = 0.f;
      if (tid < 512) {
        nx_i = b2f(xpT[(size_t)(ehidx) * 1024 + mnext]);
        nx_f = b2f(xpT[(size_t)(1024 + ehidx) * 1024 + mnext]);
        nx_g = b2f(xpT[(size_t)(2048 + ehidx) * 1024 + mnext]);
        nx_o = b2f(xpT[(size_t)(3072 + ehidx) * 1024 + mnext]);
      }
      if (w == 0) {
        unsigned tgt = (unsigned)(t + 1);
        for (;;) {
          unsigned vfl = __hip_atomic_load(&flags[lane * 16], __ATOMIC_RELAXED, __HIP_MEMORY_SCOPE_AGENT);
          if (__all(vfl >= tgt)) break;
          __builtin_amdgcn_s_sleep(1);
        }
        __builtin_amdgcn_fence(__ATOMIC_ACQUIRE, "agent");  // buffer_inv: drop stale clean h lines
      }
      __syncthreads();
      xf_i = nx_i; xf_f = nx_f; xf_g = nx_g; xf_o = nx_o;
    }
  }
}

extern "C" void kernel_launch(void* const* d_in, const int* in_sizes, int n_in,
                              void* d_out, int out_size, void* d_ws, size_t ws_size,
                              hipStream_t stream) {
  const float* inp = (const float*)d_in[0];
  const float* ctx = (const float*)d_in[1];
  const float* Wih = (const float*)d_in[2];
  const float* Whh = (const float*)d_in[3];
  const float* bih = (const float*)d_in[4];
  const float* bhh = (const float*)d_in[5];
  const float* W1  = (const float*)d_in[6];
  const float* W2  = (const float*)d_in[8];
  float* out = (float*)d_out;
  char* wsb = (char*)d_ws;

  float* v    = (float*)(wsb + 0);          // 4 KB
  float* bias = (float*)(wsb + 4096);       // 16 KB
  float* attn = (float*)(wsb + 20480);      // 8 KB
  float* wgt  = (float*)(wsb + 28672);      // 128 KB
  ushort* h0   = (ushort*)(wsb + 163840);   // 64 KB
  ushort* h1   = (ushort*)(wsb + 229376);   // 64 KB
  ushort* inpb = (ushort*)(wsb + 294912);   // 2 MB
  ushort* Wihb = (ushort*)(wsb + 2392064);  // 8 MB
  ushort* Whhb = (ushort*)(wsb + 10780672); // 8 MB
  ushort* xpT  = (ushort*)(wsb + 19169280); // 8 MB
  unsigned* flags = (unsigned*)(wsb + 27557888); // 4 KB (64 flags, 64B apart)

  hipLaunchKernelGGL(k_prep, dim3(25), dim3(256), 0, stream, W1, W2, bih, bhh, v, bias, h0, flags);
  hipLaunchKernelGGL(k_cvt3, dim3(4608), dim3(256), 0, stream, inp, inpb, Wih, Wihb, Whh, Whhb);
  hipLaunchKernelGGL(k_attn, dim3(32), dim3(256), 0, stream, ctx, v, attn, wgt);
  hipLaunchKernelGGL(k_bcast, dim3(1024), dim3(256), 0, stream, wgt, attn, out);
  hipLaunchKernelGGL(k_xproj, dim3(256), dim3(256), 0, stream, inpb, Wihb, bias, xpT);

  const ushort* Whhb_c = Whhb;
  const ushort* xpT_c = xpT;
  void* kargs[6];
  kargs[0] = (void*)&Whhb_c;
  kargs[1] = (void*)&xpT_c;
  kargs[2] = (void*)&h0;
  kargs[3] = (void*)&h1;
  kargs[4] = (void*)&out;
  kargs[5] = (void*)&flags;
  hipLaunchCooperativeKernel((const void*)k_rec, dim3(NWG), dim3(1024), kargs, 0, stream);
}

// Round 7
// 240.306 us; speedup vs baseline: 3.3688x; 1.6753x over previous
//
#include <hip/hip_runtime.h>

#define T_ 32
#define B_ 32
#define S_ 64
#define C_ 1024
#define H_ 1024
#define NWG 64

typedef __attribute__((ext_vector_type(8))) short bf16x8;
typedef __attribute__((ext_vector_type(4))) float f32x4;

// d_out layout (float offsets): outputs[32*32*1024], h[32*1024], c[32*1024], attn[32*32*64]
#define OUT_H   1048576
#define OUT_CC  1081344
#define OUT_AT  1114112

__device__ __forceinline__ ushort f2b(float f) {
  unsigned u = __float_as_uint(f);
  unsigned r = (u + 0x7FFFu + ((u >> 16) & 1u)) >> 16;
  return (ushort)r;
}
__device__ __forceinline__ float b2f(ushort h) {
  return __uint_as_float(((unsigned)h) << 16);
}

// ---------------- convert f32 -> bf16, 3 arrays in one launch ----------------
__global__ __launch_bounds__(256) void k_cvt3(const float* __restrict__ s0, ushort* __restrict__ d0,
                                              const float* __restrict__ s1, ushort* __restrict__ d1,
                                              const float* __restrict__ s2, ushort* __restrict__ d2) {
  int blk = blockIdx.x;
  const float* src;
  ushort* dst;
  int base;
  if (blk < 512) { src = s0; dst = d0; base = blk; }
  else if (blk < 2560) { src = s1; dst = d1; base = blk - 512; }
  else { src = s2; dst = d2; base = blk - 2560; }
  size_t i = ((size_t)base * 256 + threadIdx.x) * 8;
  float4 v0 = *reinterpret_cast<const float4*>(src + i);
  float4 v1 = *reinterpret_cast<const float4*>(src + i + 4);
  uint4 o;
  o.x = (unsigned)f2b(v0.x) | ((unsigned)f2b(v0.y) << 16);
  o.y = (unsigned)f2b(v0.z) | ((unsigned)f2b(v0.w) << 16);
  o.z = (unsigned)f2b(v1.x) | ((unsigned)f2b(v1.y) << 16);
  o.w = (unsigned)f2b(v1.z) | ((unsigned)f2b(v1.w) << 16);
  *reinterpret_cast<uint4*>(dst + i) = o;
}

// ---------------- prep: v = W2@W1_x, bias, zero h0, zero flags ----------------
__global__ __launch_bounds__(256) void k_prep(const float* __restrict__ W1, const float* __restrict__ W2,
                                              const float* __restrict__ bih, const float* __restrict__ bhh,
                                              float* __restrict__ v, float* __restrict__ bias,
                                              ushort* __restrict__ h0, unsigned* __restrict__ flags) {
  int blk = blockIdx.x, tid = threadIdx.x;
  if (blk < 4) {
    int c = blk * 256 + tid;
    float acc = 0.f;
#pragma unroll 8
    for (int a = 0; a < 128; ++a) acc += W1[a * 2048 + 1024 + c] * W2[a];
    v[c] = acc;
  } else if (blk < 20) {
    int j = (blk - 4) * 256 + tid;
    bias[j] = bih[j] + bhh[j];
  } else if (blk < 24) {
    unsigned* hz = reinterpret_cast<unsigned*>(h0);
    int base = (blk - 20) * 4096;
    for (int i = 0; i < 16; ++i) hz[base + i * 256 + tid] = 0u;
  } else {
    for (int i = 0; i < 4; ++i) flags[i * 256 + tid] = 0u;
  }
}

// ---------------- attention (time-invariant) ----------------
__global__ __launch_bounds__(256) void k_attn(const float* __restrict__ ctx, const float* __restrict__ v,
                                              float* __restrict__ attn, float* __restrict__ wgt) {
  int b = blockIdx.x, tid = threadIdx.x;
  int lane = tid & 63, w = tid >> 6;
  __shared__ float v_s[1024];
  __shared__ float sc_s[64];
  __shared__ float att_s[64];
  for (int i = 0; i < 4; ++i) v_s[tid + i * 256] = v[tid + i * 256];
  __syncthreads();
  for (int si = 0; si < 16; ++si) {
    int s = w * 16 + si;
    const float* xr = ctx + (size_t)(s * B_ + b) * C_;
    float acc = 0.f;
#pragma unroll
    for (int i = 0; i < 16; ++i) { int c = lane + i * 64; acc += xr[c] * v_s[c]; }
    for (int off = 32; off; off >>= 1) acc += __shfl_down(acc, off);
    if (lane == 0) sc_s[s] = acc;
  }
  __syncthreads();
  if (tid < 64) {
    float val = sc_s[tid];
    float mx = val;
    for (int off = 32; off; off >>= 1) mx = fmaxf(mx, __shfl_xor(mx, off));
    float e = expf(val - mx);
    float sm = e;
    for (int off = 32; off; off >>= 1) sm += __shfl_xor(sm, off);
    float a = e / sm;
    att_s[tid] = a;
    attn[b * 64 + tid] = a;
  }
  __syncthreads();
  const float4* ctx4 = reinterpret_cast<const float4*>(ctx);
  float4 a4 = {0.f, 0.f, 0.f, 0.f};
  for (int s = 0; s < 64; ++s) {
    float a = att_s[s];
    float4 x = ctx4[(size_t)(s * B_ + b) * 256 + tid];
    a4.x += a * x.x; a4.y += a * x.y; a4.z += a * x.z; a4.w += a * x.w;
  }
  reinterpret_cast<float4*>(wgt + b * 1024)[tid] = a4;
}

__global__ __launch_bounds__(256) void k_bcast(const float* __restrict__ wgt, const float* __restrict__ attn,
                                               float* __restrict__ out) {
  int blk = blockIdx.x, tid = threadIdx.x;
  int t = blk >> 5, b = blk & 31;
  const float4* src = reinterpret_cast<const float4*>(wgt + b * 1024);
  float4* dst = reinterpret_cast<float4*>(out + (size_t)(t * B_ + b) * C_);
  dst[tid] = src[tid];
  if (tid < 64) out[OUT_AT + (t * B_ + b) * 64 + tid] = attn[b * 64 + tid];
}

// ---------------- x_proj MFMA: xpT[j][m] = sum_k inp[m][k]*W_ih[j][k] + bias[j] ----------------
__global__ __launch_bounds__(256) void k_xproj(const ushort* __restrict__ inpb, const ushort* __restrict__ Wihb,
                                               const float* __restrict__ bias, ushort* __restrict__ xpT) {
  __shared__ int4 A_s[512];  // fragment-contiguous: [kgrp(4)][row(128)] x 16B
  __shared__ int4 B_s[512];
  int tid = threadIdx.x;
  int m0 = (blockIdx.x >> 5) << 7;
  int j0 = (blockIdx.x & 31) << 7;
  int lane = tid & 63, w = tid >> 6;
  int wm = (w >> 1) * 64, wn = (w & 1) * 64;
  int g = lane >> 4, r = lane & 15;
  f32x4 acc[4][4];
#pragma unroll
  for (int mi = 0; mi < 4; ++mi)
#pragma unroll
    for (int ni = 0; ni < 4; ++ni) acc[mi][ni] = (f32x4)(0.f);

  int f0 = tid, r0s = f0 >> 2, g0s = f0 & 3;
  int f1 = tid + 256, r1s = f1 >> 2, g1s = f1 & 3;
  for (int k0 = 0; k0 < 1024; k0 += 32) {
    __syncthreads();
    A_s[g0s * 128 + r0s] = *reinterpret_cast<const int4*>(inpb + (size_t)(m0 + r0s) * 1024 + k0 + g0s * 8);
    B_s[g0s * 128 + r0s] = *reinterpret_cast<const int4*>(Wihb + (size_t)(j0 + r0s) * 1024 + k0 + g0s * 8);
    A_s[g1s * 128 + r1s] = *reinterpret_cast<const int4*>(inpb + (size_t)(m0 + r1s) * 1024 + k0 + g1s * 8);
    B_s[g1s * 128 + r1s] = *reinterpret_cast<const int4*>(Wihb + (size_t)(j0 + r1s) * 1024 + k0 + g1s * 8);
    __syncthreads();
    bf16x8 af[4], bf_[4];
#pragma unroll
    for (int mi = 0; mi < 4; ++mi) af[mi] = *reinterpret_cast<const bf16x8*>(&A_s[g * 128 + wm + mi * 16 + r]);
#pragma unroll
    for (int ni = 0; ni < 4; ++ni) bf_[ni] = *reinterpret_cast<const bf16x8*>(&B_s[g * 128 + wn + ni * 16 + r]);
#pragma unroll
    for (int mi = 0; mi < 4; ++mi)
#pragma unroll
      for (int ni = 0; ni < 4; ++ni)
        acc[mi][ni] = __builtin_amdgcn_mfma_f32_16x16x32_bf16(af[mi], bf_[ni], acc[mi][ni], 0, 0, 0);
  }
  int q = lane >> 4;
#pragma unroll
  for (int ni = 0; ni < 4; ++ni) {
    int j = j0 + wn + ni * 16 + r;
    float bj = bias[j];
#pragma unroll
    for (int mi = 0; mi < 4; ++mi) {
      int mb = m0 + wm + mi * 16 + q * 4;
      uint2 pk;
      pk.x = (unsigned)f2b(acc[mi][ni][0] + bj) | ((unsigned)f2b(acc[mi][ni][1] + bj) << 16);
      pk.y = (unsigned)f2b(acc[mi][ni][2] + bj) | ((unsigned)f2b(acc[mi][ni][3] + bj) << 16);
      *reinterpret_cast<uint2*>(xpT + (size_t)j * 1024 + mb) = pk;
    }
  }
}

// ---------------- persistent recurrence: all 32 LSTM steps, one dispatch ----------------
// 64 WGs x 1024 threads. WG owns hidx [16*wg,16*wg+16) x 4 gates. Wave w: q=w&3 (hidx quad),
// ks=w>>2 (K-slice of 256). W_hh in registers. Per step: stage full h (64 KB) into
// XOR-swizzled LDS via agent-scope (L2-bypass) loads -> MFMA from LDS -> epilogue ->
// publish h via agent-scope stores + monotonic flag; 64-lane flag poll. NO cache fences.
__global__ __launch_bounds__(1024, 4) void k_rec(const ushort* __restrict__ Whhb, const ushort* __restrict__ xpT,
                                                 ushort* __restrict__ h0, ushort* __restrict__ h1,
                                                 float* __restrict__ out, unsigned* __restrict__ flags) {
  int tid = threadIdx.x, lane = tid & 63, w = tid >> 6;
  int wg = blockIdx.x;
  int q = w & 3, ks = w >> 2;
  int g = lane >> 4, r = lane & 15;
  int hidx0 = wg * 16 + q * 4;
  int kbase = ks * 256;
  int j = (r >> 2) * 1024 + hidx0 + (r & 3);
  bf16x8 a[8];
  {
    const ushort* ap = Whhb + (size_t)j * 1024 + kbase + g * 8;
#pragma unroll
    for (int kk = 0; kk < 8; ++kk) a[kk] = *reinterpret_cast<const bf16x8*>(ap + kk * 32);
  }
  __shared__ uint4 hl4[4096];           // 64 KB staged h: [row(32)][c16(128)], idx = row*128 + (c16 ^ (row&7))
  __shared__ float red[4][4][16][32];   // 32 KB K-slice partials
  __shared__ __align__(16) ushort hs[32][16];
  float c_reg = 0.f;
  int eb = tid & 31, hl = (tid >> 5) & 3, qq = tid >> 7;  // epilogue cell (tid<512)
  int ehidx = wg * 16 + qq * 4 + hl;

  // staging assignment: thread stages chunks ch = tid + jj*1024 (16B each)
  int s_row[4], s_c16[4];
#pragma unroll
  for (int jj = 0; jj < 4; ++jj) {
    int ch = tid + jj * 1024;
    s_row[jj] = ch >> 7;
    s_c16[jj] = ch & 127;
  }

  // prefetch xpT slice for t=0 (cached loads; xpT stays L2-resident — no invs anywhere)
  float xf_i = 0.f, xf_f = 0.f, xf_g = 0.f, xf_o = 0.f;
  if (tid < 512) {
    xf_i = b2f(xpT[(size_t)(ehidx) * 1024 + eb]);
    xf_f = b2f(xpT[(size_t)(1024 + ehidx) * 1024 + eb]);
    xf_g = b2f(xpT[(size_t)(2048 + ehidx) * 1024 + eb]);
    xf_o = b2f(xpT[(size_t)(3072 + ehidx) * 1024 + eb]);
  }

#pragma unroll 1
  for (int t = 0; t < T_; ++t) {
    const ushort* hin = (t & 1) ? h1 : h0;
    ushort* hout = (t & 1) ? h0 : h1;
    // ---- stage h -> LDS (agent-scope bypass loads; swizzled write) ----
#pragma unroll
    for (int jj = 0; jj < 4; ++jj) {
      unsigned long long* gp = (unsigned long long*)(hin + (size_t)s_row[jj] * 1024 + s_c16[jj] * 8);
      unsigned long long lo = __hip_atomic_load(gp, __ATOMIC_RELAXED, __HIP_MEMORY_SCOPE_AGENT);
      unsigned long long hi = __hip_atomic_load(gp + 1, __ATOMIC_RELAXED, __HIP_MEMORY_SCOPE_AGENT);
      uint4 vv;
      vv.x = (unsigned)lo; vv.y = (unsigned)(lo >> 32);
      vv.z = (unsigned)hi; vv.w = (unsigned)(hi >> 32);
      hl4[s_row[jj] * 128 + (s_c16[jj] ^ (s_row[jj] & 7))] = vv;
    }
    __syncthreads();
    // ---- MFMA from LDS ----
    f32x4 acc0 = (f32x4)(0.f), acc1 = (f32x4)(0.f);
    int cb = ks * 32 + g;
#pragma unroll
    for (int kk = 0; kk < 8; ++kk) {
      int c16 = cb + kk * 4;
      bf16x8 b0 = *reinterpret_cast<const bf16x8*>(&hl4[r * 128 + (c16 ^ (r & 7))]);
      bf16x8 b1 = *reinterpret_cast<const bf16x8*>(&hl4[(r + 16) * 128 + (c16 ^ (r & 7))]);
      acc0 = __builtin_amdgcn_mfma_f32_16x16x32_bf16(a[kk], b0, acc0, 0, 0, 0);
      acc1 = __builtin_amdgcn_mfma_f32_16x16x32_bf16(a[kk], b1, acc1, 0, 0, 0);
    }
#pragma unroll
    for (int e = 0; e < 4; ++e) {
      red[q][ks][g * 4 + e][r] = acc0[e];
      red[q][ks][g * 4 + e][r + 16] = acc1[e];
    }
    __syncthreads();
    if (tid < 512) {
      float ig = red[qq][0][0 + hl][eb]  + red[qq][1][0 + hl][eb]  + red[qq][2][0 + hl][eb]  + red[qq][3][0 + hl][eb]  + xf_i;
      float fg = red[qq][0][4 + hl][eb]  + red[qq][1][4 + hl][eb]  + red[qq][2][4 + hl][eb]  + red[qq][3][4 + hl][eb]  + xf_f;
      float gg = red[qq][0][8 + hl][eb]  + red[qq][1][8 + hl][eb]  + red[qq][2][8 + hl][eb]  + red[qq][3][8 + hl][eb]  + xf_g;
      float og = red[qq][0][12 + hl][eb] + red[qq][1][12 + hl][eb] + red[qq][2][12 + hl][eb] + red[qq][3][12 + hl][eb] + xf_o;
      float si = 1.f / (1.f + __expf(-ig));
      float sf = 1.f / (1.f + __expf(-fg));
      float so = 1.f / (1.f + __expf(-og));
      float c_new = sf * c_reg + si * tanhf(gg);
      float h_new = so * tanhf(c_new);
      c_reg = c_new;
      hs[eb][qq * 4 + hl] = f2b(h_new);
      if (t == T_ - 1) {
        out[OUT_H + eb * 1024 + ehidx] = h_new;
        out[OUT_CC + eb * 1024 + ehidx] = c_new;
      }
    }
    if (t != T_ - 1) {
      __syncthreads();  // hs ready
      int mnext = (t + 1) * 32 + eb;
      if (w == 0) {
        // publish h slice via agent-scope (coherence-point) dword stores
        int b = lane >> 1, half = lane & 1;
        uint4 vv = *reinterpret_cast<const uint4*>(&hs[b][half * 8]);
        unsigned* hp = reinterpret_cast<unsigned*>(hout) + b * 512 + wg * 8 + half * 4;
        __hip_atomic_store(hp + 0, vv.x, __ATOMIC_RELAXED, __HIP_MEMORY_SCOPE_AGENT);
        __hip_atomic_store(hp + 1, vv.y, __ATOMIC_RELAXED, __HIP_MEMORY_SCOPE_AGENT);
        __hip_atomic_store(hp + 2, vv.z, __ATOMIC_RELAXED, __HIP_MEMORY_SCOPE_AGENT);
        __hip_atomic_store(hp + 3, vv.w, __ATOMIC_RELAXED, __HIP_MEMORY_SCOPE_AGENT);
        asm volatile("s_waitcnt vmcnt(0)" ::: "memory");
        if (lane == 0)
          __hip_atomic_store(&flags[wg * 16], (unsigned)(t + 1), __ATOMIC_RELAXED, __HIP_MEMORY_SCOPE_AGENT);
      }
      // prefetch next xpT slice (overlaps the poll)
      float nx_i = 0.f, nx_f = 0.f, nx_g = 0.f, nx_o = 0.f;
      if (tid < 512) {
        nx_i = b2f(xpT[(size_t)(ehidx) * 1024 + mnext]);
        nx_f = b2f(xpT[(size_t)(1024 + ehidx) * 1024 + mnext]);
        nx_g = b2f(xpT[(size_t)(2048 + ehidx) * 1024 + mnext]);
        nx_o = b2f(xpT[(size_t)(3072 + ehidx) * 1024 + mnext]);
      }
      if (w == 0) {
        unsigned tgt = (unsigned)(t + 1);
        for (;;) {
          unsigned vfl = __hip_atomic_load(&flags[lane * 16], __ATOMIC_RELAXED, __HIP_MEMORY_SCOPE_AGENT);
          if (__all(vfl >= tgt)) break;
          __builtin_amdgcn_s_sleep(1);
        }
      }
      __syncthreads();
      xf_i = nx_i; xf_f = nx_f; xf_g = nx_g; xf_o = nx_o;
    }
  }
}

extern "C" void kernel_launch(void* const* d_in, const int* in_sizes, int n_in,
                              void* d_out, int out_size, void* d_ws, size_t ws_size,
                              hipStream_t stream) {
  const float* inp = (const float*)d_in[0];
  const float* ctx = (const float*)d_in[1];
  const float* Wih = (const float*)d_in[2];
  const float* Whh = (const float*)d_in[3];
  const float* bih = (const float*)d_in[4];
  const float* bhh = (const float*)d_in[5];
  const float* W1  = (const float*)d_in[6];
  const float* W2  = (const float*)d_in[8];
  float* out = (float*)d_out;
  char* wsb = (char*)d_ws;

  float* v    = (float*)(wsb + 0);          // 4 KB
  float* bias = (float*)(wsb + 4096);       // 16 KB
  float* attn = (float*)(wsb + 20480);      // 8 KB
  float* wgt  = (float*)(wsb + 28672);      // 128 KB
  ushort* h0   = (ushort*)(wsb + 163840);   // 64 KB
  ushort* h1   = (ushort*)(wsb + 229376);   // 64 KB
  ushort* inpb = (ushort*)(wsb + 294912);   // 2 MB
  ushort* Wihb = (ushort*)(wsb + 2392064);  // 8 MB
  ushort* Whhb = (ushort*)(wsb + 10780672); // 8 MB
  ushort* xpT  = (ushort*)(wsb + 19169280); // 8 MB
  unsigned* flags = (unsigned*)(wsb + 27557888); // 4 KB (64 flags, 64B apart)

  hipLaunchKernelGGL(k_prep, dim3(25), dim3(256), 0, stream, W1, W2, bih, bhh, v, bias, h0, flags);
  hipLaunchKernelGGL(k_cvt3, dim3(4608), dim3(256), 0, stream, inp, inpb, Wih, Wihb, Whh, Whhb);
  hipLaunchKernelGGL(k_attn, dim3(32), dim3(256), 0, stream, ctx, v, attn, wgt);
  hipLaunchKernelGGL(k_bcast, dim3(1024), dim3(256), 0, stream, wgt, attn, out);
  hipLaunchKernelGGL(k_xproj, dim3(256), dim3(256), 0, stream, inpb, Wihb, bias, xpT);

  const ushort* Whhb_c = Whhb;
  const ushort* xpT_c = xpT;
  void* kargs[6];
  kargs[0] = (void*)&Whhb_c;
  kargs[1] = (void*)&xpT_c;
  kargs[2] = (void*)&h0;
  kargs[3] = (void*)&h1;
  kargs[4] = (void*)&out;
  kargs[5] = (void*)&flags;
  hipLaunchCooperativeKernel((const void*)k_rec, dim3(NWG), dim3(1024), kargs, 0, stream);
}

// Round 8
// 223.175 us; speedup vs baseline: 3.6273x; 1.0768x over previous
//
#include <hip/hip_runtime.h>

#define T_ 32
#define B_ 32
#define S_ 64
#define C_ 1024
#define H_ 1024
#define NWG 64
#define HSLOT 32768  // ushorts per h ring slot (32 x 1024)

typedef __attribute__((ext_vector_type(8))) short bf16x8;
typedef __attribute__((ext_vector_type(4))) float f32x4;

// d_out layout (float offsets): outputs[32*32*1024], h[32*1024], c[32*1024], attn[32*32*64]
#define OUT_H   1048576
#define OUT_CC  1081344
#define OUT_AT  1114112

__device__ __forceinline__ ushort f2b(float f) {
  unsigned u = __float_as_uint(f);
  unsigned r = (u + 0x7FFFu + ((u >> 16) & 1u)) >> 16;
  return (ushort)r;
}
__device__ __forceinline__ float b2f(ushort h) {
  return __uint_as_float(((unsigned)h) << 16);
}

// ---------------- convert f32 -> bf16, 3 arrays in one launch ----------------
__global__ __launch_bounds__(256) void k_cvt3(const float* __restrict__ s0, ushort* __restrict__ d0,
                                              const float* __restrict__ s1, ushort* __restrict__ d1,
                                              const float* __restrict__ s2, ushort* __restrict__ d2) {
  int blk = blockIdx.x;
  const float* src;
  ushort* dst;
  int base;
  if (blk < 512) { src = s0; dst = d0; base = blk; }
  else if (blk < 2560) { src = s1; dst = d1; base = blk - 512; }
  else { src = s2; dst = d2; base = blk - 2560; }
  size_t i = ((size_t)base * 256 + threadIdx.x) * 8;
  float4 v0 = *reinterpret_cast<const float4*>(src + i);
  float4 v1 = *reinterpret_cast<const float4*>(src + i + 4);
  uint4 o;
  o.x = (unsigned)f2b(v0.x) | ((unsigned)f2b(v0.y) << 16);
  o.y = (unsigned)f2b(v0.z) | ((unsigned)f2b(v0.w) << 16);
  o.z = (unsigned)f2b(v1.x) | ((unsigned)f2b(v1.y) << 16);
  o.w = (unsigned)f2b(v1.z) | ((unsigned)f2b(v1.w) << 16);
  *reinterpret_cast<uint4*>(dst + i) = o;
}

// ---------------- prep: v = W2@W1_x, bias, zero h ring slot 0, zero flags ----------------
__global__ __launch_bounds__(256) void k_prep(const float* __restrict__ W1, const float* __restrict__ W2,
                                              const float* __restrict__ bih, const float* __restrict__ bhh,
                                              float* __restrict__ v, float* __restrict__ bias,
                                              ushort* __restrict__ hring, unsigned* __restrict__ flags) {
  int blk = blockIdx.x, tid = threadIdx.x;
  if (blk < 4) {
    int c = blk * 256 + tid;
    float acc = 0.f;
#pragma unroll 8
    for (int a = 0; a < 128; ++a) acc += W1[a * 2048 + 1024 + c] * W2[a];
    v[c] = acc;
  } else if (blk < 20) {
    int j = (blk - 4) * 256 + tid;
    bias[j] = bih[j] + bhh[j];
  } else if (blk < 24) {
    unsigned* hz = reinterpret_cast<unsigned*>(hring);
    int base = (blk - 20) * 4096;
    for (int i = 0; i < 16; ++i) hz[base + i * 256 + tid] = 0u;
  } else {
    for (int i = 0; i < 4; ++i) flags[i * 256 + tid] = 0u;
  }
}

// ---------------- attention (time-invariant) + broadcast to all t ----------------
__global__ __launch_bounds__(256) void k_attn(const float* __restrict__ ctx, const float* __restrict__ v,
                                              float* __restrict__ out) {
  int b = blockIdx.x, tid = threadIdx.x;
  int lane = tid & 63, w = tid >> 6;
  __shared__ float v_s[1024];
  __shared__ float sc_s[64];
  __shared__ float att_s[64];
  for (int i = 0; i < 4; ++i) v_s[tid + i * 256] = v[tid + i * 256];
  __syncthreads();
  for (int si = 0; si < 16; ++si) {
    int s = w * 16 + si;
    const float* xr = ctx + (size_t)(s * B_ + b) * C_;
    float acc = 0.f;
#pragma unroll
    for (int i = 0; i < 16; ++i) { int c = lane + i * 64; acc += xr[c] * v_s[c]; }
    for (int off = 32; off; off >>= 1) acc += __shfl_down(acc, off);
    if (lane == 0) sc_s[s] = acc;
  }
  __syncthreads();
  if (tid < 64) {
    float val = sc_s[tid];
    float mx = val;
    for (int off = 32; off; off >>= 1) mx = fmaxf(mx, __shfl_xor(mx, off));
    float e = expf(val - mx);
    float sm = e;
    for (int off = 32; off; off >>= 1) sm += __shfl_xor(sm, off);
    att_s[tid] = e / sm;
  }
  __syncthreads();
  const float4* ctx4 = reinterpret_cast<const float4*>(ctx);
  float4 a4 = {0.f, 0.f, 0.f, 0.f};
  for (int s = 0; s < 64; ++s) {
    float a = att_s[s];
    float4 x = ctx4[(size_t)(s * B_ + b) * 256 + tid];
    a4.x += a * x.x; a4.y += a * x.y; a4.z += a * x.z; a4.w += a * x.w;
  }
#pragma unroll 4
  for (int t = 0; t < T_; ++t)
    reinterpret_cast<float4*>(out + (size_t)(t * B_ + b) * C_)[tid] = a4;
  if (tid < 64) {
    float av = att_s[tid];
#pragma unroll 4
    for (int t = 0; t < T_; ++t) out[OUT_AT + (t * B_ + b) * 64 + tid] = av;
  }
}

// ---------------- x_proj MFMA: xpT[j][m] = sum_k inp[m][k]*W_ih[j][k] + bias[j] ----------------
__global__ __launch_bounds__(256) void k_xproj(const ushort* __restrict__ inpb, const ushort* __restrict__ Wihb,
                                               const float* __restrict__ bias, ushort* __restrict__ xpT) {
  __shared__ int4 A_s[512];  // fragment-contiguous: [kgrp(4)][row(128)] x 16B
  __shared__ int4 B_s[512];
  int tid = threadIdx.x;
  int m0 = (blockIdx.x >> 5) << 7;
  int j0 = (blockIdx.x & 31) << 7;
  int lane = tid & 63, w = tid >> 6;
  int wm = (w >> 1) * 64, wn = (w & 1) * 64;
  int g = lane >> 4, r = lane & 15;
  f32x4 acc[4][4];
#pragma unroll
  for (int mi = 0; mi < 4; ++mi)
#pragma unroll
    for (int ni = 0; ni < 4; ++ni) acc[mi][ni] = (f32x4)(0.f);

  int f0 = tid, r0s = f0 >> 2, g0s = f0 & 3;
  int f1 = tid + 256, r1s = f1 >> 2, g1s = f1 & 3;
  for (int k0 = 0; k0 < 1024; k0 += 32) {
    __syncthreads();
    A_s[g0s * 128 + r0s] = *reinterpret_cast<const int4*>(inpb + (size_t)(m0 + r0s) * 1024 + k0 + g0s * 8);
    B_s[g0s * 128 + r0s] = *reinterpret_cast<const int4*>(Wihb + (size_t)(j0 + r0s) * 1024 + k0 + g0s * 8);
    A_s[g1s * 128 + r1s] = *reinterpret_cast<const int4*>(inpb + (size_t)(m0 + r1s) * 1024 + k0 + g1s * 8);
    B_s[g1s * 128 + r1s] = *reinterpret_cast<const int4*>(Wihb + (size_t)(j0 + r1s) * 1024 + k0 + g1s * 8);
    __syncthreads();
    bf16x8 af[4], bf_[4];
#pragma unroll
    for (int mi = 0; mi < 4; ++mi) af[mi] = *reinterpret_cast<const bf16x8*>(&A_s[g * 128 + wm + mi * 16 + r]);
#pragma unroll
    for (int ni = 0; ni < 4; ++ni) bf_[ni] = *reinterpret_cast<const bf16x8*>(&B_s[g * 128 + wn + ni * 16 + r]);
#pragma unroll
    for (int mi = 0; mi < 4; ++mi)
#pragma unroll
      for (int ni = 0; ni < 4; ++ni)
        acc[mi][ni] = __builtin_amdgcn_mfma_f32_16x16x32_bf16(af[mi], bf_[ni], acc[mi][ni], 0, 0, 0);
  }
  int q = lane >> 4;
#pragma unroll
  for (int ni = 0; ni < 4; ++ni) {
    int j = j0 + wn + ni * 16 + r;
    float bj = bias[j];
#pragma unroll
    for (int mi = 0; mi < 4; ++mi) {
      int mb = m0 + wm + mi * 16 + q * 4;
      uint2 pk;
      pk.x = (unsigned)f2b(acc[mi][ni][0] + bj) | ((unsigned)f2b(acc[mi][ni][1] + bj) << 16);
      pk.y = (unsigned)f2b(acc[mi][ni][2] + bj) | ((unsigned)f2b(acc[mi][ni][3] + bj) << 16);
      *reinterpret_cast<uint2*>(xpT + (size_t)j * 1024 + mb) = pk;
    }
  }
}

// ---------------- persistent recurrence: all 32 LSTM steps, one dispatch ----------------
// 64 WGs x 1024 threads. WG owns hidx [16*wg,16*wg+16) x 4 gates. Wave w: q=w&3, ks=w>>2.
// W_hh in registers. h lives in a 33-slot ring: slot t read (CACHED loads — each slot is
// written exactly once per launch so cached lines can never be stale; L2 amortizes across
// the 8 WGs of an XCD), slot t+1 published via agent-scope (L2-bypass) stores + monotonic
// per-WG flag; readers poll 64 flags with one 64-lane bypass load. No cache fences at all.
__global__ __launch_bounds__(1024, 4) void k_rec(const ushort* __restrict__ Whhb, const ushort* __restrict__ xpT,
                                                 ushort* __restrict__ hring,
                                                 float* __restrict__ out, unsigned* __restrict__ flags) {
  int tid = threadIdx.x, lane = tid & 63, w = tid >> 6;
  int wg = blockIdx.x;
  int q = w & 3, ks = w >> 2;
  int g = lane >> 4, r = lane & 15;
  int hidx0 = wg * 16 + q * 4;
  int kbase = ks * 256;
  int j = (r >> 2) * 1024 + hidx0 + (r & 3);
  bf16x8 a[8];
  {
    const ushort* ap = Whhb + (size_t)j * 1024 + kbase + g * 8;
#pragma unroll
    for (int kk = 0; kk < 8; ++kk) a[kk] = *reinterpret_cast<const bf16x8*>(ap + kk * 32);
  }
  __shared__ uint4 hl4[4096];           // 64 KB staged h: [row(32)][c16(128)], idx = row*128 + (c16 ^ (row&7))
  __shared__ float red[4][4][16][32];   // 32 KB K-slice partials
  __shared__ __align__(16) ushort hs[32][16];
  float c_reg = 0.f;
  int eb = tid & 31, hl = (tid >> 5) & 3, qq = tid >> 7;  // epilogue cell (tid<512)
  int ehidx = wg * 16 + qq * 4 + hl;

  // staging: thread stages 16B chunks ch = tid + jj*1024 (row = ch>>7, c16 = ch&127)
  // prefetch xpT slice for t=0 (cached; stays L2-resident — no invalidations anywhere)
  float xf_i = 0.f, xf_f = 0.f, xf_g = 0.f, xf_o = 0.f;
  if (tid < 512) {
    xf_i = b2f(xpT[(size_t)(ehidx) * 1024 + eb]);
    xf_f = b2f(xpT[(size_t)(1024 + ehidx) * 1024 + eb]);
    xf_g = b2f(xpT[(size_t)(2048 + ehidx) * 1024 + eb]);
    xf_o = b2f(xpT[(size_t)(3072 + ehidx) * 1024 + eb]);
  }

#pragma unroll 1
  for (int t = 0; t < T_; ++t) {
    const uint4* hin4 = reinterpret_cast<const uint4*>(hring + (size_t)t * HSLOT);
    ushort* hout = hring + (size_t)(t + 1) * HSLOT;
    // ---- stage h -> LDS (plain cached wide loads; swizzled LDS write) ----
    {
      uint4 v0 = hin4[tid];
      uint4 v1 = hin4[tid + 1024];
      uint4 v2 = hin4[tid + 2048];
      uint4 v3 = hin4[tid + 3072];
      int ch0 = tid, ch1 = tid + 1024, ch2 = tid + 2048, ch3 = tid + 3072;
      hl4[(ch0 >> 7) * 128 + ((ch0 & 127) ^ ((ch0 >> 7) & 7))] = v0;
      hl4[(ch1 >> 7) * 128 + ((ch1 & 127) ^ ((ch1 >> 7) & 7))] = v1;
      hl4[(ch2 >> 7) * 128 + ((ch2 & 127) ^ ((ch2 >> 7) & 7))] = v2;
      hl4[(ch3 >> 7) * 128 + ((ch3 & 127) ^ ((ch3 >> 7) & 7))] = v3;
    }
    __syncthreads();
    // ---- MFMA from LDS ----
    f32x4 acc0 = (f32x4)(0.f), acc1 = (f32x4)(0.f);
    int cb = ks * 32 + g;
#pragma unroll
    for (int kk = 0; kk < 8; ++kk) {
      int c16 = cb + kk * 4;
      bf16x8 b0 = *reinterpret_cast<const bf16x8*>(&hl4[r * 128 + (c16 ^ (r & 7))]);
      bf16x8 b1 = *reinterpret_cast<const bf16x8*>(&hl4[(r + 16) * 128 + (c16 ^ (r & 7))]);
      acc0 = __builtin_amdgcn_mfma_f32_16x16x32_bf16(a[kk], b0, acc0, 0, 0, 0);
      acc1 = __builtin_amdgcn_mfma_f32_16x16x32_bf16(a[kk], b1, acc1, 0, 0, 0);
    }
#pragma unroll
    for (int e = 0; e < 4; ++e) {
      red[q][ks][g * 4 + e][r] = acc0[e];
      red[q][ks][g * 4 + e][r + 16] = acc1[e];
    }
    __syncthreads();
    if (tid < 512) {
      float ig = red[qq][0][0 + hl][eb]  + red[qq][1][0 + hl][eb]  + red[qq][2][0 + hl][eb]  + red[qq][3][0 + hl][eb]  + xf_i;
      float fg = red[qq][0][4 + hl][eb]  + red[qq][1][4 + hl][eb]  + red[qq][2][4 + hl][eb]  + red[qq][3][4 + hl][eb]  + xf_f;
      float gg = red[qq][0][8 + hl][eb]  + red[qq][1][8 + hl][eb]  + red[qq][2][8 + hl][eb]  + red[qq][3][8 + hl][eb]  + xf_g;
      float og = red[qq][0][12 + hl][eb] + red[qq][1][12 + hl][eb] + red[qq][2][12 + hl][eb] + red[qq][3][12 + hl][eb] + xf_o;
      float si = 1.f / (1.f + __expf(-ig));
      float sf = 1.f / (1.f + __expf(-fg));
      float so = 1.f / (1.f + __expf(-og));
      float c_new = sf * c_reg + si * tanhf(gg);
      float h_new = so * tanhf(c_new);
      c_reg = c_new;
      hs[eb][qq * 4 + hl] = f2b(h_new);
      if (t == T_ - 1) {
        out[OUT_H + eb * 1024 + ehidx] = h_new;
        out[OUT_CC + eb * 1024 + ehidx] = c_new;
      }
    }
    if (t != T_ - 1) {
      __syncthreads();  // hs ready
      int mnext = (t + 1) * 32 + eb;
      if (w == 0) {
        // publish h slice via agent-scope (coherence-point) dword stores
        int b = lane >> 1, half = lane & 1;
        uint4 vv = *reinterpret_cast<const uint4*>(&hs[b][half * 8]);
        unsigned* hp = reinterpret_cast<unsigned*>(hout) + b * 512 + wg * 8 + half * 4;
        __hip_atomic_store(hp + 0, vv.x, __ATOMIC_RELAXED, __HIP_MEMORY_SCOPE_AGENT);
        __hip_atomic_store(hp + 1, vv.y, __ATOMIC_RELAXED, __HIP_MEMORY_SCOPE_AGENT);
        __hip_atomic_store(hp + 2, vv.z, __ATOMIC_RELAXED, __HIP_MEMORY_SCOPE_AGENT);
        __hip_atomic_store(hp + 3, vv.w, __ATOMIC_RELAXED, __HIP_MEMORY_SCOPE_AGENT);
        asm volatile("s_waitcnt vmcnt(0)" ::: "memory");
        if (lane == 0)
          __hip_atomic_store(&flags[wg * 16], (unsigned)(t + 1), __ATOMIC_RELAXED, __HIP_MEMORY_SCOPE_AGENT);
      }
      // prefetch next xpT slice (overlaps the poll)
      float nx_i = 0.f, nx_f = 0.f, nx_g = 0.f, nx_o = 0.f;
      if (tid < 512) {
        nx_i = b2f(xpT[(size_t)(ehidx) * 1024 + mnext]);
        nx_f = b2f(xpT[(size_t)(1024 + ehidx) * 1024 + mnext]);
        nx_g = b2f(xpT[(size_t)(2048 + ehidx) * 1024 + mnext]);
        nx_o = b2f(xpT[(size_t)(3072 + ehidx) * 1024 + mnext]);
      }
      if (w == 0) {
        unsigned tgt = (unsigned)(t + 1);
        for (;;) {
          unsigned vfl = __hip_atomic_load(&flags[lane * 16], __ATOMIC_RELAXED, __HIP_MEMORY_SCOPE_AGENT);
          if (__all(vfl >= tgt)) break;
          __builtin_amdgcn_s_sleep(1);
        }
      }
      __syncthreads();
      xf_i = nx_i; xf_f = nx_f; xf_g = nx_g; xf_o = nx_o;
    }
  }
}

extern "C" void kernel_launch(void* const* d_in, const int* in_sizes, int n_in,
                              void* d_out, int out_size, void* d_ws, size_t ws_size,
                              hipStream_t stream) {
  const float* inp = (const float*)d_in[0];
  const float* ctx = (const float*)d_in[1];
  const float* Wih = (const float*)d_in[2];
  const float* Whh = (const float*)d_in[3];
  const float* bih = (const float*)d_in[4];
  const float* bhh = (const float*)d_in[5];
  const float* W1  = (const float*)d_in[6];
  const float* W2  = (const float*)d_in[8];
  float* out = (float*)d_out;
  char* wsb = (char*)d_ws;

  float* v    = (float*)(wsb + 0);          // 4 KB
  float* bias = (float*)(wsb + 4096);       // 16 KB
  ushort* hring = (ushort*)(wsb + 32768);   // 33 slots x 64 KB = 2112 KB
  ushort* inpb = (ushort*)(wsb + 2195456);  // 2 MB
  ushort* Wihb = (ushort*)(wsb + 4292608);  // 8 MB
  ushort* Whhb = (ushort*)(wsb + 12681216); // 8 MB
  ushort* xpT  = (ushort*)(wsb + 21069824); // 8 MB
  unsigned* flags = (unsigned*)(wsb + 29458432); // 4 KB (64 flags, 64B apart)

  hipLaunchKernelGGL(k_prep, dim3(25), dim3(256), 0, stream, W1, W2, bih, bhh, v, bias, hring, flags);
  hipLaunchKernelGGL(k_cvt3, dim3(4608), dim3(256), 0, stream, inp, inpb, Wih, Wihb, Whh, Whhb);
  hipLaunchKernelGGL(k_attn, dim3(32), dim3(256), 0, stream, ctx, v, out);
  hipLaunchKernelGGL(k_xproj, dim3(256), dim3(256), 0, stream, inpb, Wihb, bias, xpT);

  const ushort* Whhb_c = Whhb;
  const ushort* xpT_c = xpT;
  void* kargs[5];
  kargs[0] = (void*)&Whhb_c;
  kargs[1] = (void*)&xpT_c;
  kargs[2] = (void*)&hring;
  kargs[3] = (void*)&out;
  kargs[4] = (void*)&flags;
  hipLaunchCooperativeKernel((const void*)k_rec, dim3(NWG), dim3(1024), kargs, 0, stream);
}